// Round 1
// baseline (237.428 us; speedup 1.0000x reference)
//
#include <hip/hip_runtime.h>

#define HW_ (512*512)
#define NCH 32
#define NIMG 4
#define NCLS 19
#define ALPHA_ 0.05f
#define BETA_ 1.0f

// workspace float offsets
#define WS_SEG   0        // [4][19][32] class sums
#define WS_CNT   2432     // [4][19]     class counts
#define WS_MEAN  2508     // [4][19][32] class means
#define WS_INUM  4940     // [4] intra numerator
#define WS_ICNT  4944     // [4] intra valid count
#define WS_IVAL  4948     // [4] per-image inter value
#define WS_ZERO_FLOATS 4952

#define REP 4  // LDS accumulator replicas (cuts same-address atomic serialization)

// ---------------- Pass 1: per-class sum of normalized embeddings + counts ----
__global__ __launch_bounds__(256) void k_pass1(const float* __restrict__ emb,
                                               const int* __restrict__ lab,
                                               float* __restrict__ ws)
{
    const int n = blockIdx.y;
    __shared__ float sseg[REP][NCLS][NCH + 1]; // +1 pad: bank = (l*33+c)%32 varies with l
    __shared__ float scnt[REP][NCLS];
    for (int t = threadIdx.x; t < REP * NCLS * (NCH + 1); t += blockDim.x)
        (&sseg[0][0][0])[t] = 0.f;
    for (int t = threadIdx.x; t < REP * NCLS; t += blockDim.x)
        (&scnt[0][0])[t] = 0.f;
    __syncthreads();

    const int rep = (threadIdx.x >> 4) & (REP - 1);
    const float* ebase = emb + (size_t)n * NCH * HW_;
    const int*   lbase = lab + (size_t)n * HW_;

    for (int p = blockIdx.x * blockDim.x + threadIdx.x; p < HW_;
         p += gridDim.x * blockDim.x) {
        float v[NCH];
        float ss = 0.f;
        #pragma unroll
        for (int c = 0; c < NCH; ++c) {
            v[c] = ebase[(size_t)c * HW_ + p];
            ss += v[c] * v[c];
        }
        float rn = 1.f / fmaxf(sqrtf(ss), 1e-12f);
        int l = lbase[p];
        if (l == 255) l = 0;
        float* srow = sseg[rep][l];
        #pragma unroll
        for (int c = 0; c < NCH; ++c)
            atomicAdd(&srow[c], v[c] * rn);
        atomicAdd(&scnt[rep][l], 1.f);
    }
    __syncthreads();

    // merge replicas in LDS, one global atomic per value
    float* seg = ws + WS_SEG + (size_t)n * NCLS * NCH;
    float* cnt = ws + WS_CNT + (size_t)n * NCLS;
    for (int t = threadIdx.x; t < NCLS * NCH; t += blockDim.x) {
        int k = t >> 5, c = t & 31;
        float s = 0.f;
        #pragma unroll
        for (int r = 0; r < REP; ++r) s += sseg[r][k][c];
        atomicAdd(&seg[t], s);
    }
    for (int t = threadIdx.x; t < NCLS; t += blockDim.x) {
        float s = 0.f;
        #pragma unroll
        for (int r = 0; r < REP; ++r) s += scnt[r][t];
        atomicAdd(&cnt[t], s);
    }
}

// ---------------- Stats: means, D matrix, per-image inter --------------------
__global__ __launch_bounds__(512) void k_stats(float* __restrict__ ws)
{
    const int n = blockIdx.x;
    __shared__ float smean[NCLS][NCH + 1];
    __shared__ float scnt[NCLS];
    __shared__ float snum, sden;
    if (threadIdx.x == 0) { snum = 0.f; sden = 0.f; }
    for (int t = threadIdx.x; t < NCLS; t += blockDim.x)
        scnt[t] = ws[WS_CNT + n * NCLS + t];
    __syncthreads();

    for (int t = threadIdx.x; t < NCLS * NCH; t += blockDim.x) {
        int k = t >> 5, c = t & 31;
        float m = ws[WS_SEG + n * NCLS * NCH + t] / (scnt[k] + 1.f);
        smean[k][c] = m;
        ws[WS_MEAN + n * NCLS * NCH + t] = m;
    }
    __syncthreads();

    for (int t = threadIdx.x; t < NCLS * NCLS; t += blockDim.x) {
        int i = t / NCLS, j = t - i * NCLS;
        float D = 0.f;
        #pragma unroll
        for (int c = 0; c < NCH; ++c) {
            float df = smean[i][c] - smean[j][c];
            D += df * df;
        }
        float pres = (scnt[i] > 0.f && scnt[j] > 0.f) ? 1.f : 0.f;
        D *= pres;
        bool im = (D < BETA_) && (D > 0.f);
        if (i >= 1 && im) {
            atomicAdd(&sden, 1.f);
            if (j >= 1) atomicAdd(&snum, BETA_ - D);
        }
    }
    __syncthreads();
    if (threadIdx.x == 0)
        ws[WS_IVAL + n] = snum / (sden + 1.f) * 0.5f;
}

// ---------------- Pass 2: per-pixel distance to class mean -------------------
__global__ __launch_bounds__(256) void k_pass2(const float* __restrict__ emb,
                                               const int* __restrict__ lab,
                                               float* __restrict__ ws)
{
    const int n = blockIdx.y;
    __shared__ float smean[NCLS][NCH + 1];
    __shared__ float bnum, bcnt;
    for (int t = threadIdx.x; t < NCLS * NCH; t += blockDim.x)
        smean[t >> 5][t & 31] = ws[WS_MEAN + n * NCLS * NCH + t];
    if (threadIdx.x == 0) { bnum = 0.f; bcnt = 0.f; }
    __syncthreads();

    const float* ebase = emb + (size_t)n * NCH * HW_;
    const int*   lbase = lab + (size_t)n * HW_;
    float lnum = 0.f, lcnt = 0.f;

    for (int p = blockIdx.x * blockDim.x + threadIdx.x; p < HW_;
         p += gridDim.x * blockDim.x) {
        float v[NCH];
        float ss = 0.f;
        #pragma unroll
        for (int c = 0; c < NCH; ++c) {
            v[c] = ebase[(size_t)c * HW_ + p];
            ss += v[c] * v[c];
        }
        float rn = 1.f / fmaxf(sqrtf(ss), 1e-12f);
        int l = lbase[p];
        if (l == 255) l = 0;
        const float* m = smean[l]; // same-address LDS reads broadcast (free)
        float d = 0.f;
        #pragma unroll
        for (int c = 0; c < NCH; ++c) {
            float df = m[c] - v[c] * rn;
            d += df * df;
        }
        if (l > 0 && d > ALPHA_) { lnum += d - ALPHA_; lcnt += 1.f; }
    }

    // wave (64-lane) shuffle reduction
    for (int o = 32; o > 0; o >>= 1) {
        lnum += __shfl_down(lnum, o);
        lcnt += __shfl_down(lcnt, o);
    }
    if ((threadIdx.x & 63) == 0) { atomicAdd(&bnum, lnum); atomicAdd(&bcnt, lcnt); }
    __syncthreads();
    if (threadIdx.x == 0) {
        atomicAdd(&ws[WS_INUM + n], bnum);
        atomicAdd(&ws[WS_ICNT + n], bcnt);
    }
}

// ---------------- Final scalar combine ---------------------------------------
__global__ void k_final(const float* __restrict__ ws, float* __restrict__ out)
{
    if (threadIdx.x == 0 && blockIdx.x == 0) {
        float intra = 0.f, inter = 0.f;
        for (int n = 0; n < NIMG; ++n) {
            intra += ws[WS_INUM + n] / (ws[WS_ICNT + n] + 1.f);
            inter += ws[WS_IVAL + n];
        }
        out[0] = intra * 0.25f;
        out[1] = inter * 0.25f;
    }
}

extern "C" void kernel_launch(void* const* d_in, const int* in_sizes, int n_in,
                              void* d_out, int out_size, void* d_ws, size_t ws_size,
                              hipStream_t stream)
{
    const float* emb = (const float*)d_in[0];
    const int*   lab = (const int*)d_in[1];
    float* ws  = (float*)d_ws;
    float* out = (float*)d_out;

    // zero accumulator region each launch (harness does not re-poison between replays)
    hipMemsetAsync(d_ws, 0, WS_ZERO_FLOATS * sizeof(float), stream);

    dim3 g1(256, NIMG); // 1024 blocks, 4 px/thread
    k_pass1<<<g1, 256, 0, stream>>>(emb, lab, ws);

    k_stats<<<NIMG, 512, 0, stream>>>(ws);

    dim3 g2(512, NIMG); // 2048 blocks, 2 px/thread
    k_pass2<<<g2, 256, 0, stream>>>(emb, lab, ws);

    k_final<<<1, 64, 0, stream>>>(ws, out);
}